// Round 4
// baseline (675.771 us; speedup 1.0000x reference)
//
#include <hip/hip_runtime.h>

#define B_SZ 8192
#define LAT  64
#define ADIM 16
#define DM   128
#define DI   256
#define NST  16
#define NB   2
#define ROWS 16
#define NT   256

#define Z_OFF  0
#define RW_OFF (B_SZ * LAT)          /* 524288 */
#define DN_OFF (RW_OFF + B_SZ)       /* 532480 */
#define H_OFF  (DN_OFF + B_SZ)       /* 540672 */

__device__ __forceinline__ float softplus_f(float v) {
    // matches jax.nn.softplus = max(v,0) + log1p(exp(-|v|))
    return fmaxf(v, 0.f) + log1pf(expf(-fabsf(v)));
}
__device__ __forceinline__ float silu_f(float z) {
    return z / (1.f + expf(-z));
}
__device__ __forceinline__ float dot4(float4 a, float4 b, float acc) {
    acc = fmaf(a.x, b.x, acc);
    acc = fmaf(a.y, b.y, acc);
    acc = fmaf(a.z, b.z, acc);
    acc = fmaf(a.w, b.w, acc);
    return acc;
}

__global__ __launch_bounds__(NT) void mamba_wm_kernel(
    const float* __restrict__ z_t,       // (8192,64)
    const int*   __restrict__ action,    // (8192)
    const float* __restrict__ h_in,      // (2,8192,256,16)
    const float* __restrict__ a_embed,   // (9,16)
    const float* __restrict__ fusion_w,  // (128,80)
    const float* __restrict__ fusion_b,  // (128)
    const float* __restrict__ norm_g,    // (2,128)
    const float* __restrict__ norm_b,    // (2,128)
    const float* __restrict__ in_proj_w, // (2,512,128)
    const float* __restrict__ x_proj_w,  // (2,33,256)
    const float* __restrict__ log_A,     // (2,256,16)
    const float* __restrict__ dt_bias,   // (2,256)
    const float* __restrict__ Dp,        // (2,256)
    const float* __restrict__ out_proj_w,// (2,128,256)
    const float* __restrict__ ns_w1, const float* __restrict__ ns_b1,
    const float* __restrict__ ns_w2, const float* __restrict__ ns_b2,
    const float* __restrict__ rw_w1, const float* __restrict__ rw_b1,
    const float* __restrict__ rw_w2, const float* __restrict__ rw_b2,
    const float* __restrict__ dn_w1, const float* __restrict__ dn_b1,
    const float* __restrict__ dn_w2, const float* __restrict__ dn_b2,
    float* __restrict__ out)
{
    // Padded strides: 132 (128+4) and 260 (256+4) keep float4 alignment
    // (multiples of 4 floats) and break power-of-2 bank aliasing (2-way max
    // across rows, which is free on CDNA4 — learn_hip m136).
    __shared__ __align__(16) float s_x [ROWS][132]; // current x / residual
    __shared__ __align__(16) float s_xn[ROWS][132]; // layernorm out (also fusion input staging)
    __shared__ __align__(16) float s_xm[ROWS][260]; // x_main, later y
    __shared__ __align__(16) float s_z [ROWS][260]; // gate z
    __shared__ __align__(16) float s_xp[ROWS][36];  // B(16),C(16),dt(1)

    const int t    = threadIdx.x;
    const int row0 = blockIdx.x * ROWS;

    // ---------------- P0: stage fusion inputs [z_t | a_emb] into s_xn[r][0..79]
    for (int idx = t; idx < ROWS * 80; idx += NT) {
        int r = idx / 80;
        int k = idx - r * 80;
        int row = row0 + r;
        float v;
        if (k < LAT) v = z_t[(size_t)row * LAT + k];
        else         v = a_embed[action[row] * ADIM + (k - LAT)];
        s_xn[r][k] = v;
    }
    __syncthreads();

    // ---------------- P1: fusion matmul + ReLU -> s_x
    {
        const int j  = t & 127;
        const int rb = t >> 7;       // 0 or 1
        const float* wrow = fusion_w + j * 80;
        float acc[8];
        #pragma unroll
        for (int rr = 0; rr < 8; ++rr) acc[rr] = fusion_b[j];
        for (int k = 0; k < 80; k += 4) {
            float4 w4 = *reinterpret_cast<const float4*>(wrow + k);
            #pragma unroll
            for (int rr = 0; rr < 8; ++rr) {
                int r = rb + 2 * rr;
                float4 x4 = *reinterpret_cast<const float4*>(&s_xn[r][k]);
                acc[rr] = dot4(w4, x4, acc[rr]);
            }
        }
        #pragma unroll
        for (int rr = 0; rr < 8; ++rr)
            s_x[rb + 2 * rr][j] = fmaxf(acc[rr], 0.f);
    }
    __syncthreads();

    // ---------------- SSM blocks (sequential dependency, all in-LDS per WG)
    for (int blk = 0; blk < NB; ++blk) {
        const float* ng  = norm_g     + blk * DM;
        const float* nbv = norm_b     + blk * DM;
        const float* inw = in_proj_w  + (size_t)blk * 2 * DI * DM;
        const float* xpw = x_proj_w   + (size_t)blk * 33 * DI;
        const float* lA  = log_A      + (size_t)blk * DI * NST;
        const float* dtb = dt_bias    + blk * DI;
        const float* dpv = Dp         + blk * DI;
        const float* ow  = out_proj_w + (size_t)blk * DM * DI;

        // ---- P2: layernorm over DM=128, 16 threads per row
        {
            const int r = t >> 4;
            const int l = t & 15;
            float s = 0.f;
            #pragma unroll
            for (int m = 0; m < 8; ++m) s += s_x[r][l + 16 * m];
            #pragma unroll
            for (int m = 1; m < 16; m <<= 1) s += __shfl_xor(s, m, 64);
            float mu = s * (1.f / 128.f);
            float v = 0.f;
            #pragma unroll
            for (int m = 0; m < 8; ++m) {
                float d = s_x[r][l + 16 * m] - mu;
                v = fmaf(d, d, v);
            }
            #pragma unroll
            for (int m = 1; m < 16; m <<= 1) v += __shfl_xor(v, m, 64);
            float rstd = 1.f / sqrtf(v * (1.f / 128.f) + 1e-5f);
            #pragma unroll
            for (int m = 0; m < 8; ++m) {
                int k = l + 16 * m;
                s_xn[r][k] = (s_x[r][k] - mu) * rstd * ng[k] + nbv[k];
            }
        }
        __syncthreads();

        // ---- P3: in_proj (512x128). thread t -> x_main col t and z col t
        {
            const float* wa = inw + (size_t)t * DM;        // x_main row
            const float* wb = inw + (size_t)(t + DI) * DM; // z row
            float aa[ROWS], ab[ROWS];
            #pragma unroll
            for (int r = 0; r < ROWS; ++r) { aa[r] = 0.f; ab[r] = 0.f; }
            for (int k = 0; k < DM; k += 4) {
                float4 w4a = *reinterpret_cast<const float4*>(wa + k);
                float4 w4b = *reinterpret_cast<const float4*>(wb + k);
                #pragma unroll
                for (int r = 0; r < ROWS; ++r) {
                    float4 x4 = *reinterpret_cast<const float4*>(&s_xn[r][k]);
                    aa[r] = dot4(w4a, x4, aa[r]);
                    ab[r] = dot4(w4b, x4, ab[r]);
                }
            }
            #pragma unroll
            for (int r = 0; r < ROWS; ++r) {
                s_xm[r][t] = aa[r];
                s_z [r][t] = ab[r];
            }
        }
        __syncthreads();

        // ---- P4: x_proj (33x256) -> s_xp[r][0..32]
        for (int it = t; it < ROWS * 33; it += NT) {
            int r = it / 33;
            int j = it - r * 33;
            const float* w = xpw + (size_t)j * DI;
            float acc = 0.f;
            for (int k = 0; k < DI; k += 4) {
                float4 w4 = *reinterpret_cast<const float4*>(w + k);
                float4 x4 = *reinterpret_cast<const float4*>(&s_xm[r][k]);
                acc = dot4(w4, x4, acc);
            }
            s_xp[r][j] = acc;
        }
        __syncthreads();

        // ---- P5: SSM state update + y reduction. thread t -> channel d=t.
        {
            const int d = t;
            float Av[NST];
            #pragma unroll
            for (int n = 0; n < NST; ++n) Av[n] = expf(lA[d * NST + n]);
            const float dtbd = dtb[d];
            const float Dvd  = dpv[d];
            const float* hbase = h_in + (((size_t)blk * B_SZ + row0) * DI + d) * NST;
            float*       obase = out + H_OFF + (((size_t)blk * B_SZ + row0) * DI + d) * NST;

            // 2-deep pipeline on the h row loads (64B/thread/row, coalesced)
            float4 p0 = *reinterpret_cast<const float4*>(hbase + 0);
            float4 p1 = *reinterpret_cast<const float4*>(hbase + 4);
            float4 p2 = *reinterpret_cast<const float4*>(hbase + 8);
            float4 p3 = *reinterpret_cast<const float4*>(hbase + 12);

            for (int r = 0; r < ROWS; ++r) {
                float4 q0 = p0, q1 = p1, q2 = p2, q3 = p3;
                if (r + 1 < ROWS) {
                    const float* hn = hbase + (size_t)(r + 1) * DI * NST;
                    p0 = *reinterpret_cast<const float4*>(hn + 0);
                    p1 = *reinterpret_cast<const float4*>(hn + 4);
                    p2 = *reinterpret_cast<const float4*>(hn + 8);
                    p3 = *reinterpret_cast<const float4*>(hn + 12);
                }
                float xm    = s_xm[r][d];
                float zz    = s_z [r][d];
                float delta = softplus_f(s_xp[r][32] + dtbd);
                float dxm   = delta * xm;

                float hv[16], Bv[16], Cv[16];
                *reinterpret_cast<float4*>(hv + 0)  = q0;
                *reinterpret_cast<float4*>(hv + 4)  = q1;
                *reinterpret_cast<float4*>(hv + 8)  = q2;
                *reinterpret_cast<float4*>(hv + 12) = q3;
                *reinterpret_cast<float4*>(Bv + 0)  = *reinterpret_cast<const float4*>(&s_xp[r][0]);
                *reinterpret_cast<float4*>(Bv + 4)  = *reinterpret_cast<const float4*>(&s_xp[r][4]);
                *reinterpret_cast<float4*>(Bv + 8)  = *reinterpret_cast<const float4*>(&s_xp[r][8]);
                *reinterpret_cast<float4*>(Bv + 12) = *reinterpret_cast<const float4*>(&s_xp[r][12]);
                *reinterpret_cast<float4*>(Cv + 0)  = *reinterpret_cast<const float4*>(&s_xp[r][16]);
                *reinterpret_cast<float4*>(Cv + 4)  = *reinterpret_cast<const float4*>(&s_xp[r][20]);
                *reinterpret_cast<float4*>(Cv + 8)  = *reinterpret_cast<const float4*>(&s_xp[r][24]);
                *reinterpret_cast<float4*>(Cv + 12) = *reinterpret_cast<const float4*>(&s_xp[r][28]);

                float y = 0.f;
                #pragma unroll
                for (int n = 0; n < 16; ++n) {
                    float ab = expf(-delta * Av[n]);
                    float hn = fmaf(ab, hv[n], dxm * Bv[n]);
                    y = fmaf(hn, Cv[n], y);
                    hv[n] = hn;
                }
                float* ho = obase + (size_t)r * DI * NST;
                *reinterpret_cast<float4*>(ho + 0)  = *reinterpret_cast<float4*>(hv + 0);
                *reinterpret_cast<float4*>(ho + 4)  = *reinterpret_cast<float4*>(hv + 4);
                *reinterpret_cast<float4*>(ho + 8)  = *reinterpret_cast<float4*>(hv + 8);
                *reinterpret_cast<float4*>(ho + 12) = *reinterpret_cast<float4*>(hv + 12);

                y = fmaf(Dvd, xm, y);
                s_xm[r][d] = y * silu_f(zz);   // y * silu(z), overwrite own slot
            }
        }
        __syncthreads();

        // ---- P6: out_proj (128x256) + residual -> s_x
        {
            const int j  = t & 127;
            const int rb = t >> 7;
            const float* w = ow + (size_t)j * DI;
            float acc[8];
            #pragma unroll
            for (int rr = 0; rr < 8; ++rr) acc[rr] = 0.f;
            for (int k = 0; k < DI; k += 4) {
                float4 w4 = *reinterpret_cast<const float4*>(w + k);
                #pragma unroll
                for (int rr = 0; rr < 8; ++rr) {
                    int r = rb + 2 * rr;
                    float4 x4 = *reinterpret_cast<const float4*>(&s_xm[r][k]);
                    acc[rr] = dot4(w4, x4, acc[rr]);
                }
            }
            #pragma unroll
            for (int rr = 0; rr < 8; ++rr) {
                int r = rb + 2 * rr;
                s_x[r][j] += acc[rr];   // own slot: residual + out_proj
            }
        }
        __syncthreads();
    }

    // ---------------- Heads ----------------
    // H1: ns hidden = relu(x @ ns_w1.T + ns_b1) -> s_xn[r][0..127]
    {
        const int j  = t & 127;
        const int rb = t >> 7;
        const float* w = ns_w1 + (size_t)j * DM;
        float acc[8];
        #pragma unroll
        for (int rr = 0; rr < 8; ++rr) acc[rr] = ns_b1[j];
        for (int k = 0; k < DM; k += 4) {
            float4 w4 = *reinterpret_cast<const float4*>(w + k);
            #pragma unroll
            for (int rr = 0; rr < 8; ++rr) {
                int r = rb + 2 * rr;
                float4 x4 = *reinterpret_cast<const float4*>(&s_x[r][k]);
                acc[rr] = dot4(w4, x4, acc[rr]);
            }
        }
        #pragma unroll
        for (int rr = 0; rr < 8; ++rr)
            s_xn[rb + 2 * rr][j] = fmaxf(acc[rr], 0.f);
    }
    // RW hidden -> s_z[r][0..63], DN hidden -> s_xm[r][0..63] (shared x4 reads)
    {
        const int o   = t & 63;
        const int rb4 = t >> 6;   // 0..3
        const float* wr = rw_w1 + (size_t)o * DM;
        const float* wd = dn_w1 + (size_t)o * DM;
        float accR[4], accD[4];
        #pragma unroll
        for (int m = 0; m < 4; ++m) { accR[m] = rw_b1[o]; accD[m] = dn_b1[o]; }
        for (int k = 0; k < DM; k += 4) {
            float4 w4r = *reinterpret_cast<const float4*>(wr + k);
            float4 w4d = *reinterpret_cast<const float4*>(wd + k);
            #pragma unroll
            for (int m = 0; m < 4; ++m) {
                int r = rb4 + 4 * m;
                float4 x4 = *reinterpret_cast<const float4*>(&s_x[r][k]);
                accR[m] = dot4(w4r, x4, accR[m]);
                accD[m] = dot4(w4d, x4, accD[m]);
            }
        }
        #pragma unroll
        for (int m = 0; m < 4; ++m) {
            int r = rb4 + 4 * m;
            s_z [r][o] = fmaxf(accR[m], 0.f);
            s_xm[r][o] = fmaxf(accD[m], 0.f);
        }
    }
    __syncthreads();

    // Z2: z_next = h1 @ ns_w2.T + ns_b2  -> out[row*64+o]
    {
        const int o   = t & 63;
        const int rb4 = t >> 6;
        const float* w = ns_w2 + (size_t)o * DM;
        float acc[4];
        #pragma unroll
        for (int m = 0; m < 4; ++m) acc[m] = ns_b2[o];
        for (int k = 0; k < DM; k += 4) {
            float4 w4 = *reinterpret_cast<const float4*>(w + k);
            #pragma unroll
            for (int m = 0; m < 4; ++m) {
                int r = rb4 + 4 * m;
                float4 x4 = *reinterpret_cast<const float4*>(&s_xn[r][k]);
                acc[m] = dot4(w4, x4, acc[m]);
            }
        }
        #pragma unroll
        for (int m = 0; m < 4; ++m) {
            int r = rb4 + 4 * m;
            out[Z_OFF + (size_t)(row0 + r) * LAT + o] = acc[m];
        }
    }
    // reward / done scalar heads (tiny)
    if (t < 32) {
        const int r    = t & 15;
        const bool isR = (t < 16);
        const float* w2 = isR ? rw_w2 : dn_w2;
        const float  b2 = isR ? rw_b2[0] : dn_b2[0];
        float acc = b2;
        if (isR) {
            for (int k = 0; k < 64; ++k) acc = fmaf(s_z[r][k], w2[k], acc);
            out[RW_OFF + row0 + r] = acc;
        } else {
            for (int k = 0; k < 64; ++k) acc = fmaf(s_xm[r][k], w2[k], acc);
            out[DN_OFF + row0 + r] = acc;
        }
    }
}

extern "C" void kernel_launch(void* const* d_in, const int* in_sizes, int n_in,
                              void* d_out, int out_size, void* d_ws, size_t ws_size,
                              hipStream_t stream) {
    (void)in_sizes; (void)n_in; (void)out_size; (void)d_ws; (void)ws_size;
    mamba_wm_kernel<<<B_SZ / ROWS, NT, 0, stream>>>(
        (const float*)d_in[0],  (const int*)d_in[1],   (const float*)d_in[2],
        (const float*)d_in[3],  (const float*)d_in[4], (const float*)d_in[5],
        (const float*)d_in[6],  (const float*)d_in[7], (const float*)d_in[8],
        (const float*)d_in[9],  (const float*)d_in[10],(const float*)d_in[11],
        (const float*)d_in[12], (const float*)d_in[13],(const float*)d_in[14],
        (const float*)d_in[15], (const float*)d_in[16],(const float*)d_in[17],
        (const float*)d_in[18], (const float*)d_in[19],(const float*)d_in[20],
        (const float*)d_in[21], (const float*)d_in[22],(const float*)d_in[23],
        (const float*)d_in[24], (const float*)d_in[25],
        (float*)d_out);
}